// Round 8
// baseline (1530.164 us; speedup 1.0000x reference)
//
#include <hip/hip_runtime.h>

#define N_NODES   20000
#define N_EDGES   640000
#define IN_DIM    128
#define HID_DIM   256
#define N_TYPES   4
#define N_ASPECTS 4096
#define NBUCK     157                   // dst buckets of 128 nodes
#define BCAP      5120                  // bucket capacity (mean 4096 + 16 sigma)
#define CHUNK     2560                  // edges per bucketA block (250 blocks exact)
#define NGROUPS   1250                  // 16-node groups (20000/16)

typedef __bf16 v8bf __attribute__((ext_vector_type(8)));
typedef float  f32x4 __attribute__((ext_vector_type(4)));

static __device__ __forceinline__ float bf2f(unsigned short u) {
    return __builtin_bit_cast(float, ((unsigned int)u) << 16);
}
static __device__ __forceinline__ float bflo(unsigned int u) {
    return __builtin_bit_cast(float, u << 16);
}
static __device__ __forceinline__ float bfhi(unsigned int u) {
    return __builtin_bit_cast(float, u & 0xffff0000u);
}
// f32 -> bf16 round-to-nearest-even (finite values)
static __device__ __forceinline__ unsigned short f2bf(float f) {
    unsigned int u = __builtin_bit_cast(unsigned int, f);
    u += 0x7fffu + ((u >> 16) & 1u);
    return (unsigned short)(u >> 16);
}

// ---------- dtype detector: 1 = inputs are bf16, 0 = inputs are f32 --------
__global__ void detect_kernel(const unsigned short* __restrict__ w,
                              int* __restrict__ flag) {
    int tid = threadIdx.x;
    int c = 0;
    for (int i = tid; i < 8192; i += 256) {
        unsigned hb = (w[i] >> 8) & 0x7f;
        c += (hb >= 0x39 && hb <= 0x3D) ? 1 : 0;
    }
#pragma unroll
    for (int off = 32; off >= 1; off >>= 1) c += __shfl_down(c, off);
    __shared__ int red[4];
    if ((tid & 63) == 0) red[tid >> 6] = c;
    __syncthreads();
    if (tid == 0) {
        int tot = red[0] + red[1] + red[2] + red[3];
        *flag = (tot >= 6144) ? 1 : 0;
    }
}

// ---------- canonicalize x -> bf16 xc --------------------------------------
__global__ void convx_kernel(const void* __restrict__ xin,
                             const int* __restrict__ flagp,
                             unsigned short* __restrict__ xc) {
    int idx = blockIdx.x * blockDim.x + threadIdx.x;
    if (idx >= N_NODES * IN_DIM / 8) return;
    if (*flagp) {
        reinterpret_cast<uint4*>(xc)[idx] = reinterpret_cast<const uint4*>(xin)[idx];
    } else {
        const float* xf = reinterpret_cast<const float*>(xin) + (size_t)idx * 8;
        unsigned short r[8] __attribute__((aligned(16)));
#pragma unroll
        for (int j = 0; j < 8; j++) r[j] = f2bf(xf[j]);
        reinterpret_cast<uint4*>(xc)[idx] = *reinterpret_cast<const uint4*>(r);
    }
}

// ---------- pack WT[256][K] = [W_self; W_type]^T (bf16) --------------------
template <int K, int DSELF>
__global__ void packW_kernel(const void* __restrict__ Wself,
                             const void* __restrict__ Wtype,
                             const int* __restrict__ flagp,
                             unsigned short* __restrict__ WT) {
    int idx = blockIdx.x * blockDim.x + threadIdx.x;
    if (idx >= 256 * K) return;
    int n = idx / K;
    int k = idx - n * K;
    int bf = *flagp;
    const void* p = (k < DSELF) ? Wself : Wtype;
    size_t src = (k < DSELF) ? ((size_t)k * 256 + n) : ((size_t)(k - DSELF) * 256 + n);
    WT[idx] = bf ? ((const unsigned short*)p)[src]
                 : f2bf(((const float*)p)[src]);
}

// ---------- sort-based CSR build ------------------------------------------
// Pass A: block-local counting sort by dst-bucket (d>>7), bulk-append runs.
// Entry pack: s(15) | t(2)<<15 | d(15)<<17  (bucket = e>>24)
__global__ __launch_bounds__(256) void bucketA_kernel(
        const int* __restrict__ ei, const int* __restrict__ et,
        int* __restrict__ bucket_cursor, unsigned int* __restrict__ breg) {
    __shared__ unsigned int ord[CHUNK];
    __shared__ int hist[NBUCK], start[NBUCK], cur[NBUCK], gbase[NBUCK];
    int tid = threadIdx.x;
    int e0 = blockIdx.x * CHUNK;
    for (int i = tid; i < NBUCK; i += 256) hist[i] = 0;
    __syncthreads();
    unsigned int pk[10];
    int bk[10];
#pragma unroll
    for (int r = 0; r < 10; r++) {
        int e = e0 + r * 256 + tid;
        int s = __builtin_nontemporal_load(ei + e);
        int d = __builtin_nontemporal_load(ei + N_EDGES + e);
        int t = __builtin_nontemporal_load(et + e);
        pk[r] = (unsigned int)s | ((unsigned int)t << 15) | ((unsigned int)d << 17);
        bk[r] = d >> 7;
        atomicAdd(&hist[bk[r]], 1);
    }
    __syncthreads();
    if (tid == 0) {
        int acc = 0;
        for (int b = 0; b < NBUCK; b++) { start[b] = acc; cur[b] = acc; acc += hist[b]; }
    }
    __syncthreads();
#pragma unroll
    for (int r = 0; r < 10; r++) {
        int p = atomicAdd(&cur[bk[r]], 1);
        ord[p] = pk[r];
    }
    __syncthreads();
    for (int b = tid; b < NBUCK; b += 256)
        if (hist[b] > 0) gbase[b] = atomicAdd(bucket_cursor + b, hist[b]);
    __syncthreads();
    for (int p = tid; p < CHUNK; p += 256) {
        unsigned int e = ord[p];
        int b = (int)(e >> 24);
        int gp = gbase[b] + (p - start[b]);
        if (gp < BCAP)
            __builtin_nontemporal_store(e, breg + (size_t)b * BCAP + gp);
    }
}

// Small scan over the 157 bucket counts -> global output bases.
__global__ void scan157_kernel(const int* __restrict__ bucket_cursor,
                               int* __restrict__ out_base) {
    __shared__ int buf[256];
    int tid = threadIdx.x;
    int c = (tid < NBUCK) ? bucket_cursor[tid] : 0;
    if (c > BCAP) c = BCAP;
    buf[tid] = c;
    __syncthreads();
    for (int off = 1; off < 256; off <<= 1) {
        int t = (tid >= off) ? buf[tid - off] : 0;
        __syncthreads();
        buf[tid] += t;
        __syncthreads();
    }
    if (tid < NBUCK) out_base[tid] = buf[tid] - c;
}

// Pass B: per-bucket -> per-16-node-group edge runs, coarse-sorted by src
// (src>>8 counting sort). Output tag: src(15) | t(2)<<15 | ldst(4)<<17.
// Also emits goff[] run boundaries and invdeg[] per node.
__global__ __launch_bounds__(256) void bucketB_kernel(
        const unsigned int* __restrict__ breg,
        const int* __restrict__ bucket_cursor,
        const int* __restrict__ out_base,
        unsigned int* __restrict__ perm2,
        int* __restrict__ goff,
        float* __restrict__ invdeg) {
    __shared__ unsigned int ord[BCAP], ord2[BCAP];
    __shared__ int ncnt[128], gcnt[8], gpre[9], gcur[8];
    __shared__ int hist[79], hoff[79];
    int b = blockIdx.x, tid = threadIdx.x;
    int Eb = bucket_cursor[b];
    if (Eb > BCAP) Eb = BCAP;
    int obase = out_base[b];
    for (int i = tid; i < 128; i += 256) ncnt[i] = 0;
    if (tid < 8) gcnt[tid] = 0;
    __syncthreads();
    for (int i = tid; i < Eb; i += 256) {
        unsigned int e = breg[(size_t)b * BCAP + i];
        int nb = (e >> 17) & 127;
        ord[i] = e;
        atomicAdd(&ncnt[nb], 1);
        atomicAdd(&gcnt[nb >> 4], 1);
    }
    __syncthreads();
    if (tid == 0) {
        int a = 0;
        for (int g = 0; g < 8; g++) { gpre[g] = a; gcur[g] = a; a += gcnt[g]; }
        gpre[8] = a;
    }
    __syncthreads();
    if (tid < 8) goff[b * 8 + tid] = obase + gpre[tid];
    for (int i = tid; i < 128; i += 256) {
        int node = b * 128 + i;
        if (node < N_NODES) invdeg[node] = 1.0f / (float)(ncnt[i] > 1 ? ncnt[i] : 1);
    }
    // bin by group, repack tag
    for (int i = tid; i < Eb; i += 256) {
        unsigned int e = ord[i];
        int p = atomicAdd(&gcur[((e >> 17) & 127) >> 4], 1);
        ord2[p] = (e & 0x1ffffu) | (((e >> 17) & 15u) << 17);
    }
    __syncthreads();
    // per-group coarse counting sort by src>>8 (bins 0..78)
    for (int g = 0; g < 8; g++) {
        int s = gpre[g], epos = gpre[g + 1];
        for (int i = tid; i < 79; i += 256) hist[i] = 0;
        __syncthreads();
        for (int i = s + tid; i < epos; i += 256)
            atomicAdd(&hist[(ord2[i] >> 8) & 127], 1);
        __syncthreads();
        if (tid == 0) {
            int a = 0;
            for (int k = 0; k < 79; k++) { hoff[k] = a; a += hist[k]; }
        }
        __syncthreads();
        for (int i = s + tid; i < epos; i += 256) {
            unsigned int e = ord2[i];
            int p = atomicAdd(&hoff[(e >> 8) & 127], 1);
            ord[s + p] = e;
        }
        __syncthreads();
    }
    for (int i = tid; i < Eb; i += 256) perm2[obase + i] = ord[i];
}

// ---------- sliding-window aggregation: block per 16-node group ------------
// acc[16][4][D] f32 in LDS (ds_add_f32); edges processed in coarse-src order
// so the chip-wide gather sweeps F like a sliding window (L2-resident).
template <int D>
__global__ __launch_bounds__(256) void agg_kernel(
        const unsigned short* __restrict__ F,     // [N, D] bf16
        const int* __restrict__ goff,             // [NGROUPS+1] run bounds
        const unsigned int* __restrict__ perm2,   // [E] tags, src-coarse-sorted
        const float* __restrict__ invdeg,         // [N]
        unsigned short* __restrict__ AG) {        // [N, 4*D] bf16
    constexpr int V = D / 64;                     // elems per lane: 2 or 4
    __shared__ float acc[64 * D];                 // 16 nodes * 4 types * D
    int tid = threadIdx.x;
    int g = blockIdx.x;
    int base = goff[g], end = goff[g + 1];
    for (int i = tid; i < 64 * D; i += 256) acc[i] = 0.f;
    __syncthreads();
    int wave = tid >> 6, lane = tid & 63;
    int nch = (end - base + 63) >> 6;
    for (int c = wave; c < nch; c += 4) {
        int cb = base + (c << 6);
        int m = end - cb; if (m > 64) m = 64;
        unsigned int tag = (lane < m) ? perm2[cb + lane] : 0u;
        int i = 0;
        for (; i + 4 <= m; i += 4) {
            unsigned int t0 = (unsigned int)__shfl((int)tag, i);
            unsigned int t1 = (unsigned int)__shfl((int)tag, i + 1);
            unsigned int t2 = (unsigned int)__shfl((int)tag, i + 2);
            unsigned int t3 = (unsigned int)__shfl((int)tag, i + 3);
            if (V == 2) {
                unsigned int x0 = *reinterpret_cast<const unsigned int*>(F + (size_t)(t0 & 0x7fffu) * D + lane * 2);
                unsigned int x1 = *reinterpret_cast<const unsigned int*>(F + (size_t)(t1 & 0x7fffu) * D + lane * 2);
                unsigned int x2 = *reinterpret_cast<const unsigned int*>(F + (size_t)(t2 & 0x7fffu) * D + lane * 2);
                unsigned int x3 = *reinterpret_cast<const unsigned int*>(F + (size_t)(t3 & 0x7fffu) * D + lane * 2);
                int b0 = (int)(((t0 >> 17) * 4 + ((t0 >> 15) & 3)) * D) + lane * 2;
                int b1 = (int)(((t1 >> 17) * 4 + ((t1 >> 15) & 3)) * D) + lane * 2;
                int b2 = (int)(((t2 >> 17) * 4 + ((t2 >> 15) & 3)) * D) + lane * 2;
                int b3 = (int)(((t3 >> 17) * 4 + ((t3 >> 15) & 3)) * D) + lane * 2;
                atomicAdd(&acc[b0], bflo(x0));     atomicAdd(&acc[b0 + 1], bfhi(x0));
                atomicAdd(&acc[b1], bflo(x1));     atomicAdd(&acc[b1 + 1], bfhi(x1));
                atomicAdd(&acc[b2], bflo(x2));     atomicAdd(&acc[b2 + 1], bfhi(x2));
                atomicAdd(&acc[b3], bflo(x3));     atomicAdd(&acc[b3 + 1], bfhi(x3));
            } else {
                uint2 x0 = *reinterpret_cast<const uint2*>(F + (size_t)(t0 & 0x7fffu) * D + lane * 4);
                uint2 x1 = *reinterpret_cast<const uint2*>(F + (size_t)(t1 & 0x7fffu) * D + lane * 4);
                uint2 x2 = *reinterpret_cast<const uint2*>(F + (size_t)(t2 & 0x7fffu) * D + lane * 4);
                uint2 x3 = *reinterpret_cast<const uint2*>(F + (size_t)(t3 & 0x7fffu) * D + lane * 4);
                int b0 = (int)(((t0 >> 17) * 4 + ((t0 >> 15) & 3)) * D) + lane * 4;
                int b1 = (int)(((t1 >> 17) * 4 + ((t1 >> 15) & 3)) * D) + lane * 4;
                int b2 = (int)(((t2 >> 17) * 4 + ((t2 >> 15) & 3)) * D) + lane * 4;
                int b3 = (int)(((t3 >> 17) * 4 + ((t3 >> 15) & 3)) * D) + lane * 4;
                atomicAdd(&acc[b0], bflo(x0.x));   atomicAdd(&acc[b0 + 1], bfhi(x0.x));
                atomicAdd(&acc[b0 + 2], bflo(x0.y)); atomicAdd(&acc[b0 + 3], bfhi(x0.y));
                atomicAdd(&acc[b1], bflo(x1.x));   atomicAdd(&acc[b1 + 1], bfhi(x1.x));
                atomicAdd(&acc[b1 + 2], bflo(x1.y)); atomicAdd(&acc[b1 + 3], bfhi(x1.y));
                atomicAdd(&acc[b2], bflo(x2.x));   atomicAdd(&acc[b2 + 1], bfhi(x2.x));
                atomicAdd(&acc[b2 + 2], bflo(x2.y)); atomicAdd(&acc[b2 + 3], bfhi(x2.y));
                atomicAdd(&acc[b3], bflo(x3.x));   atomicAdd(&acc[b3 + 1], bfhi(x3.x));
                atomicAdd(&acc[b3 + 2], bflo(x3.y)); atomicAdd(&acc[b3 + 3], bfhi(x3.y));
            }
        }
        for (; i < m; i++) {
            unsigned int t0 = (unsigned int)__shfl((int)tag, i);
            int b0 = (int)(((t0 >> 17) * 4 + ((t0 >> 15) & 3)) * D) + lane * V;
            if (V == 2) {
                unsigned int x0 = *reinterpret_cast<const unsigned int*>(F + (size_t)(t0 & 0x7fffu) * D + lane * 2);
                atomicAdd(&acc[b0], bflo(x0));
                atomicAdd(&acc[b0 + 1], bfhi(x0));
            } else {
                uint2 x0 = *reinterpret_cast<const uint2*>(F + (size_t)(t0 & 0x7fffu) * D + lane * 4);
                atomicAdd(&acc[b0], bflo(x0.x));   atomicAdd(&acc[b0 + 1], bfhi(x0.x));
                atomicAdd(&acc[b0 + 2], bflo(x0.y)); atomicAdd(&acc[b0 + 3], bfhi(x0.y));
            }
        }
    }
    __syncthreads();
    // writeback: 32*D u32 units, coalesced
    int gbase = g * 16;
    for (int u = tid; u < 32 * D; u += 256) {
        int node = u / (2 * D);
        int q = (u - node * 2 * D) * 2;
        float inv = invdeg[gbase + node];
        float f0 = acc[node * 4 * D + q] * inv;
        float f1 = acc[node * 4 * D + q + 1] * inv;
        unsigned int r = (unsigned int)f2bf(f0) | ((unsigned int)f2bf(f1) << 16);
        *reinterpret_cast<unsigned int*>(AG + (size_t)(gbase + node) * 4 * D + q) = r;
    }
}

// ---------- MFMA GEMM: C[M,256] = [X | AG] @ WT^T + bias -------------------
// 64x64 tile, K-step 64, 4 waves in 2x2 (32x32 each). Grid: (N/64=4, M/64)
template <int D>
__global__ __launch_bounds__(256, 6) void gemm_kernel(
        const unsigned short* __restrict__ X,    // [M, D] bf16 (self features)
        const unsigned short* __restrict__ AG,   // [M, 4*D] bf16
        const unsigned short* __restrict__ BT,   // [256, 5*D] bf16
        const void* __restrict__ bias,           // [256] bf16 or f32 (flag)
        const int* __restrict__ flagp,
        unsigned short* __restrict__ C,          // [M, 256] bf16
        int M, int relu) {
    constexpr int K = 5 * D;
    constexpr int LDW = 72;                      // 64 + 8 pad, rows 16B-aligned
    __shared__ __align__(16) unsigned short As[64 * LDW];
    __shared__ __align__(16) unsigned short Bs[64 * LDW];
    int tid  = threadIdx.x;
    int n0   = blockIdx.x * 64;
    int m0   = blockIdx.y * 64;
    int wave = tid >> 6, lane = tid & 63;
    int wm = wave >> 1, wn = wave & 1;
    int quad = lane >> 4, l16 = lane & 15;

    f32x4 acc[2][2];
#pragma unroll
    for (int i = 0; i < 2; i++)
#pragma unroll
        for (int j = 0; j < 2; j++) acc[i][j] = (f32x4){0.f, 0.f, 0.f, 0.f};

    for (int k0 = 0; k0 < K; k0 += 64) {
        const unsigned short* base = (k0 < D) ? X : AG;
        int rs  = (k0 < D) ? D : 4 * D;
        int col = (k0 < D) ? k0 : (k0 - D);
#pragma unroll
        for (int cc = 0; cc < 2; cc++) {
            int c   = tid + cc * 256;      // 0..511
            int row = c >> 3;              // 8 uint4-chunks per 64-wide row
            int c8  = c & 7;
            uint4 va = make_uint4(0u, 0u, 0u, 0u);
            int gr = m0 + row;
            if (gr < M)
                va = *reinterpret_cast<const uint4*>(base + (size_t)gr * rs + col + c8 * 8);
            *reinterpret_cast<uint4*>(&As[row * LDW + c8 * 8]) = va;
            uint4 vb = *reinterpret_cast<const uint4*>(BT + (size_t)(n0 + row) * K + k0 + c8 * 8);
            *reinterpret_cast<uint4*>(&Bs[row * LDW + c8 * 8]) = vb;
        }
        __syncthreads();
#pragma unroll
        for (int ks = 0; ks < 2; ks++) {
            v8bf af[2], bfr[2];
#pragma unroll
            for (int i = 0; i < 2; i++)
                af[i] = *reinterpret_cast<const v8bf*>(
                    &As[(wm * 32 + i * 16 + l16) * LDW + ks * 32 + quad * 8]);
#pragma unroll
            for (int j = 0; j < 2; j++)
                bfr[j] = *reinterpret_cast<const v8bf*>(
                    &Bs[(wn * 32 + j * 16 + l16) * LDW + ks * 32 + quad * 8]);
#pragma unroll
            for (int i = 0; i < 2; i++)
#pragma unroll
                for (int j = 0; j < 2; j++)
                    acc[i][j] = __builtin_amdgcn_mfma_f32_16x16x32_bf16(af[i], bfr[j], acc[i][j], 0, 0, 0);
        }
        __syncthreads();
    }
    int bf = *flagp;
#pragma unroll
    for (int i = 0; i < 2; i++) {
#pragma unroll
        for (int j = 0; j < 2; j++) {
            int col = n0 + wn * 32 + j * 16 + l16;
            float bv = bf ? bf2f(((const unsigned short*)bias)[col])
                          : ((const float*)bias)[col];
#pragma unroll
            for (int r = 0; r < 4; r++) {
                int row = m0 + wm * 32 + i * 16 + quad * 4 + r;
                if (row < M) {
                    float v = acc[i][j][r] + bv;
                    if (relu) v = fmaxf(v, 0.0f);
                    C[(size_t)row * 256 + col] = f2bf(v);
                }
            }
        }
    }
}

// ---------- classifier head ------------------------------------------------
__global__ void cls_kernel(const unsigned short* __restrict__ h2,  // [N,256] bf16
                           const int* __restrict__ aidx,
                           const void* __restrict__ Wc,            // [256,3]
                           const void* __restrict__ bc,            // [3]
                           const int* __restrict__ flagp,
                           void* __restrict__ out) {               // [A,3]
    int lin = blockIdx.x * blockDim.x + threadIdx.x;
    int a = lin >> 6, lane = lin & 63;
    if (a >= N_ASPECTS) return;
    int bf = *flagp;
    int node = aidx[a];
    uint2 v = *reinterpret_cast<const uint2*>(h2 + (size_t)node * 256 + lane * 4);
    float hv[4] = {bflo(v.x), bfhi(v.x), bflo(v.y), bfhi(v.y)};
    float a0 = 0.f, a1 = 0.f, a2 = 0.f;
#pragma unroll
    for (int r = 0; r < 4; r++) {
        int k = lane * 4 + r;
        float w0 = bf ? bf2f(((const unsigned short*)Wc)[k * 3 + 0]) : ((const float*)Wc)[k * 3 + 0];
        float w1 = bf ? bf2f(((const unsigned short*)Wc)[k * 3 + 1]) : ((const float*)Wc)[k * 3 + 1];
        float w2 = bf ? bf2f(((const unsigned short*)Wc)[k * 3 + 2]) : ((const float*)Wc)[k * 3 + 2];
        a0 += hv[r] * w0;
        a1 += hv[r] * w1;
        a2 += hv[r] * w2;
    }
#pragma unroll
    for (int off = 32; off >= 1; off >>= 1) {
        a0 += __shfl_down(a0, off);
        a1 += __shfl_down(a1, off);
        a2 += __shfl_down(a2, off);
    }
    if (lane == 0) {
        float b0 = bf ? bf2f(((const unsigned short*)bc)[0]) : ((const float*)bc)[0];
        float b1 = bf ? bf2f(((const unsigned short*)bc)[1]) : ((const float*)bc)[1];
        float b2 = bf ? bf2f(((const unsigned short*)bc)[2]) : ((const float*)bc)[2];
        if (bf) {
            unsigned short* o = (unsigned short*)out;
            o[a * 3 + 0] = f2bf(a0 + b0);
            o[a * 3 + 1] = f2bf(a1 + b1);
            o[a * 3 + 2] = f2bf(a2 + b2);
        } else {
            float* o = (float*)out;
            o[a * 3 + 0] = a0 + b0;
            o[a * 3 + 1] = a1 + b1;
            o[a * 3 + 2] = a2 + b2;
        }
    }
}

extern "C" void kernel_launch(void* const* d_in, const int* in_sizes, int n_in,
                              void* d_out, int out_size, void* d_ws, size_t ws_size,
                              hipStream_t stream) {
    const void* x   = d_in[0];
    const void* Wt1 = d_in[1];
    const void* Ws1 = d_in[2];
    const void* b1  = d_in[3];
    const void* Wt2 = d_in[4];
    const void* Ws2 = d_in[5];
    const void* b2  = d_in[6];
    const void* Wc  = d_in[7];
    const void* bc  = d_in[8];
    const int* ei = (const int*)d_in[9];
    const int* et = (const int*)d_in[10];
    const int* ai = (const int*)d_in[11];

    char* ws = (char*)d_ws;
    size_t off = 0;
    auto alloc = [&](size_t bytes) {
        void* p = ws + off;
        off += (bytes + 255) & ~(size_t)255;
        return p;
    };
    int*            flag          = (int*)alloc(4);
    int*            bucket_cursor = (int*)alloc((size_t)NBUCK * 4);
    int*            out_base      = (int*)alloc((size_t)NBUCK * 4);
    int*            goff          = (int*)alloc((size_t)(NBUCK * 8 + 1) * 4);
    float*          invdeg        = (float*)alloc((size_t)N_NODES * 4);
    unsigned int*   breg          = (unsigned int*)alloc((size_t)NBUCK * BCAP * 4); // 3.2 MB
    unsigned int*   perm2         = (unsigned int*)alloc((size_t)N_EDGES * 4);      // 2.6 MB
    unsigned short* xc            = (unsigned short*)alloc((size_t)N_NODES * IN_DIM * 2);
    unsigned short* AG            = (unsigned short*)alloc((size_t)N_NODES * 4 * HID_DIM * 2);
    unsigned short* h             = (unsigned short*)alloc((size_t)N_NODES * HID_DIM * 2);
    unsigned short* h2            = (unsigned short*)alloc((size_t)N_NODES * HID_DIM * 2);
    unsigned short* WT1           = (unsigned short*)alloc((size_t)640 * 256 * 2);
    unsigned short* WT2           = (unsigned short*)alloc((size_t)1280 * 256 * 2);
    // total ~55 MB

    detect_kernel<<<1, 256, 0, stream>>>((const unsigned short*)Ws1, flag);
    hipMemsetAsync(bucket_cursor, 0, (size_t)NBUCK * 4, stream);
    convx_kernel<<<(N_NODES * IN_DIM / 8 + 255) / 256, 256, 0, stream>>>(x, flag, xc);
    packW_kernel<640, 128><<<640, 256, 0, stream>>>(Ws1, Wt1, flag, WT1);
    packW_kernel<1280, 256><<<1280, 256, 0, stream>>>(Ws2, Wt2, flag, WT2);

    // sort-based CSR build (group runs, coarse-src-sorted)
    bucketA_kernel<<<N_EDGES / CHUNK, 256, 0, stream>>>(ei, et, bucket_cursor, breg);
    scan157_kernel<<<1, 256, 0, stream>>>(bucket_cursor, out_base);
    bucketB_kernel<<<NBUCK, 256, 0, stream>>>(breg, bucket_cursor, out_base, perm2, goff, invdeg);

    // Layer 1
    agg_kernel<IN_DIM><<<NGROUPS, 256, 0, stream>>>(xc, goff, perm2, invdeg, AG);
    gemm_kernel<IN_DIM><<<dim3(4, 313), 256, 0, stream>>>(xc, AG, WT1, b1, flag, h, N_NODES, 1);
    // Layer 2
    agg_kernel<HID_DIM><<<NGROUPS, 256, 0, stream>>>(h, goff, perm2, invdeg, AG);
    gemm_kernel<HID_DIM><<<dim3(4, 313), 256, 0, stream>>>(h, AG, WT2, b2, flag, h2, N_NODES, 0);
    // Head
    cls_kernel<<<(N_ASPECTS * 64) / 256, 256, 0, stream>>>(h2, ai, Wc, bc, flag, d_out);
}

// Round 9
// 261.646 us; speedup vs baseline: 5.8482x; 5.8482x over previous
//
#include <hip/hip_runtime.h>

#define N_NODES   20000
#define N_EDGES   640000
#define IN_DIM    128
#define HID_DIM   256
#define N_TYPES   4
#define N_ASPECTS 4096
#define NT4       (N_NODES * N_TYPES)   // 80000 CSR segments
#define NBUCK     157                   // dst buckets of 128 nodes
#define BCAP      5120                  // bucket capacity (mean 4096 + 16 sigma)
#define CHUNK     2560                  // edges per bucketA block (250 blocks exact)

typedef __bf16 v8bf __attribute__((ext_vector_type(8)));
typedef float  f32x4 __attribute__((ext_vector_type(4)));

static __device__ __forceinline__ float bf2f(unsigned short u) {
    return __builtin_bit_cast(float, ((unsigned int)u) << 16);
}
static __device__ __forceinline__ float bflo(unsigned int u) {
    return __builtin_bit_cast(float, u << 16);
}
static __device__ __forceinline__ float bfhi(unsigned int u) {
    return __builtin_bit_cast(float, u & 0xffff0000u);
}
// f32 -> bf16 round-to-nearest-even (finite values)
static __device__ __forceinline__ unsigned short f2bf(float f) {
    unsigned int u = __builtin_bit_cast(unsigned int, f);
    u += 0x7fffu + ((u >> 16) & 1u);
    return (unsigned short)(u >> 16);
}

// Per-block dtype detection (no cross-block dependency): scans 8192 uint16s
// of W_self1; bf16 layout -> nearly all high-bytes look like small-weight
// exponents, f32 layout -> only ~half.
static __device__ __forceinline__ int local_flag(const unsigned short* w) {
    __shared__ int red[4];
    int tid = threadIdx.x;
    int c = 0;
    for (int i = tid; i < 8192; i += 256) {
        unsigned hb = (w[i] >> 8) & 0x7f;
        c += (hb >= 0x39 && hb <= 0x3D) ? 1 : 0;
    }
#pragma unroll
    for (int off = 32; off >= 1; off >>= 1) c += __shfl_down(c, off);
    if ((tid & 63) == 0) red[tid >> 6] = c;
    __syncthreads();
    int tot = red[0] + red[1] + red[2] + red[3];
    __syncthreads();
    return (tot >= 6144) ? 1 : 0;
}

// ---------- fused preprocessing: convx | packW1 | packW2 | cursor+flag -----
// Block roles: [0,1250) convx, [1250,1890) packW1, [1890,3170) packW2,
// [3170] zero bucket_cursor + publish flag for gemm/cls epilogues.
__global__ __launch_bounds__(256) void pre_kernel(
        const void* __restrict__ x,
        const void* __restrict__ Ws1, const void* __restrict__ Wt1,
        const void* __restrict__ Ws2, const void* __restrict__ Wt2,
        unsigned short* __restrict__ xc,
        unsigned short* __restrict__ WT1,
        unsigned short* __restrict__ WT2,
        int* __restrict__ bucket_cursor,
        int* __restrict__ flag) {
    int bf = local_flag((const unsigned short*)Ws1);
    int b = blockIdx.x, tid = threadIdx.x;
    if (b < 1250) {                      // convx: 320000 8-elem chunks
        int idx = b * 256 + tid;
        if (bf) {
            reinterpret_cast<uint4*>(xc)[idx] = reinterpret_cast<const uint4*>(x)[idx];
        } else {
            const float* xf = reinterpret_cast<const float*>(x) + (size_t)idx * 8;
            unsigned short r[8] __attribute__((aligned(16)));
#pragma unroll
            for (int j = 0; j < 8; j++) r[j] = f2bf(xf[j]);
            reinterpret_cast<uint4*>(xc)[idx] = *reinterpret_cast<const uint4*>(r);
        }
    } else if (b < 1890) {               // packW1: K=640, DSELF=128
        int idx = (b - 1250) * 256 + tid;
        int n = idx / 640, k = idx - n * 640;
        const void* p = (k < 128) ? Ws1 : Wt1;
        size_t src = (k < 128) ? ((size_t)k * 256 + n) : ((size_t)(k - 128) * 256 + n);
        WT1[idx] = bf ? ((const unsigned short*)p)[src] : f2bf(((const float*)p)[src]);
    } else if (b < 3170) {               // packW2: K=1280, DSELF=256
        int idx = (b - 1890) * 256 + tid;
        int n = idx / 1280, k = idx - n * 1280;
        const void* p = (k < 256) ? Ws2 : Wt2;
        size_t src = (k < 256) ? ((size_t)k * 256 + n) : ((size_t)(k - 256) * 256 + n);
        WT2[idx] = bf ? ((const unsigned short*)p)[src] : f2bf(((const float*)p)[src]);
    } else {                             // housekeeping
        if (tid < NBUCK) bucket_cursor[tid] = 0;
        if (tid == 0) *flag = bf;
    }
}

// ---------- sort-based CSR build ------------------------------------------
// Pass A: block-local counting sort by dst-bucket (d>>7), bulk-append runs.
// Entry pack: s(15) | t(2)<<15 | d(15)<<17  (bucket = e>>24)
__global__ __launch_bounds__(256) void bucketA_kernel(
        const int* __restrict__ ei, const int* __restrict__ et,
        int* __restrict__ bucket_cursor, unsigned int* __restrict__ breg) {
    __shared__ unsigned int ord[CHUNK];
    __shared__ int hist[NBUCK], start[NBUCK], cur[NBUCK], gbase[NBUCK];
    int tid = threadIdx.x;
    int e0 = blockIdx.x * CHUNK;
    for (int i = tid; i < NBUCK; i += 256) hist[i] = 0;
    __syncthreads();
    unsigned int pk[10];
    int bk[10];
#pragma unroll
    for (int r = 0; r < 10; r++) {
        int e = e0 + r * 256 + tid;
        int s = __builtin_nontemporal_load(ei + e);
        int d = __builtin_nontemporal_load(ei + N_EDGES + e);
        int t = __builtin_nontemporal_load(et + e);
        pk[r] = (unsigned int)s | ((unsigned int)t << 15) | ((unsigned int)d << 17);
        bk[r] = d >> 7;
        atomicAdd(&hist[bk[r]], 1);
    }
    __syncthreads();
    if (tid == 0) {
        int acc = 0;
        for (int b = 0; b < NBUCK; b++) { start[b] = acc; cur[b] = acc; acc += hist[b]; }
    }
    __syncthreads();
#pragma unroll
    for (int r = 0; r < 10; r++) {
        int p = atomicAdd(&cur[bk[r]], 1);
        ord[p] = pk[r];
    }
    __syncthreads();
    for (int b = tid; b < NBUCK; b += 256)
        if (hist[b] > 0) gbase[b] = atomicAdd(bucket_cursor + b, hist[b]);
    __syncthreads();
    for (int p = tid; p < CHUNK; p += 256) {
        unsigned int e = ord[p];
        int b = (int)(e >> 24);
        int gp = gbase[b] + (p - start[b]);
        if (gp < BCAP)
            __builtin_nontemporal_store(e, breg + (size_t)b * BCAP + gp);
    }
}

// Small scan over the 157 bucket counts -> global output bases.
__global__ void scan157_kernel(const int* __restrict__ bucket_cursor,
                               int* __restrict__ out_base,
                               int* __restrict__ offsets4) {
    __shared__ int buf[256];
    int tid = threadIdx.x;
    int c = (tid < NBUCK) ? bucket_cursor[tid] : 0;
    if (c > BCAP) c = BCAP;
    buf[tid] = c;
    __syncthreads();
    for (int off = 1; off < 256; off <<= 1) {
        int t = (tid >= off) ? buf[tid - off] : 0;
        __syncthreads();
        buf[tid] += t;
        __syncthreads();
    }
    if (tid < NBUCK) out_base[tid] = buf[tid] - c;
    if (tid == 0) offsets4[NT4] = buf[255];
}

// Pass B: per-bucket counting sort over 512 (node,type) segments ->
// final perm (ushort src ids) + CSR offsets4, all writes bucket-local.
__global__ __launch_bounds__(256) void bucketB_kernel(
        const unsigned int* __restrict__ breg,
        const int* __restrict__ bucket_cursor,
        const int* __restrict__ out_base,
        unsigned short* __restrict__ perm,
        int* __restrict__ offsets4) {
    __shared__ int cnt[512], off[512];
    int b = blockIdx.x, tid = threadIdx.x;
    int Eb = bucket_cursor[b];
    if (Eb > BCAP) Eb = BCAP;
    int obase = out_base[b];
    for (int i = tid; i < 512; i += 256) cnt[i] = 0;
    __syncthreads();
    const unsigned int* reg = breg + (size_t)b * BCAP;
    for (int i = tid; i < Eb; i += 256) {
        unsigned int e = reg[i];
        int seg = (((e >> 17) & 127) << 2) | ((e >> 15) & 3);
        atomicAdd(&cnt[seg], 1);
    }
    __syncthreads();
    if (tid == 0) {
        int acc = 0;
        for (int i = 0; i < 512; i++) { off[i] = acc; acc += cnt[i]; }
    }
    __syncthreads();
    for (int i = tid; i < 512; i += 256) {
        int node = b * 128 + (i >> 2);
        if (node < N_NODES) offsets4[node * 4 + (i & 3)] = obase + off[i];
    }
    __syncthreads();
    for (int i = tid; i < Eb; i += 256) {
        unsigned int e = reg[i];
        int seg = (((e >> 17) & 127) << 2) | ((e >> 15) & 3);
        int p = atomicAdd(&off[seg], 1);
        perm[obase + p] = (unsigned short)(e & 0x7fff);
    }
}

// ---------- per-node typed aggregation (wave per node, ILP=4) --------------
// R7-proven body; grid-stride over nodes with 2048 fully-resident blocks.
template <int D>
__global__ __launch_bounds__(256) void agg_kernel(
        const unsigned short* __restrict__ F,    // [N, D] bf16
        const int* __restrict__ offs4,           // [NT4+1]
        const unsigned short* __restrict__ perm, // [E] src ids, (dst,type)-sorted
        unsigned short* __restrict__ AG) {       // [N, 4*D] bf16
    constexpr int V = D / 64;                    // elems per lane: 2 or 4
    int wave = threadIdx.x >> 6, lane = threadIdx.x & 63;
    for (int n = blockIdx.x * 4 + wave; n < N_NODES; n += gridDim.x * 4) {
        int o0 = offs4[n * 4];
        int o4 = offs4[n * 4 + 4];
        int deg = o4 - o0;
        float inv = 1.0f / (float)(deg > 1 ? deg : 1);
        int s0 = o0;
#pragma unroll
        for (int t = 0; t < 4; t++) {
            int s1 = offs4[n * 4 + t + 1];
            float a[V];
#pragma unroll
            for (int v = 0; v < V; v++) a[v] = 0.f;
            int j = s0;
            while (j < s1) {
                int m = s1 - j;
                if (m > 64) m = 64;
                int pw = (lane < m) ? (int)perm[j + lane] : 0;
                int i = 0;
                for (; i + 4 <= m; i += 4) {
                    int q0 = __shfl(pw, i);
                    int q1 = __shfl(pw, i + 1);
                    int q2 = __shfl(pw, i + 2);
                    int q3 = __shfl(pw, i + 3);
                    if (V == 2) {
                        unsigned int x0 = *reinterpret_cast<const unsigned int*>(F + (size_t)q0 * D + lane * 2);
                        unsigned int x1 = *reinterpret_cast<const unsigned int*>(F + (size_t)q1 * D + lane * 2);
                        unsigned int x2 = *reinterpret_cast<const unsigned int*>(F + (size_t)q2 * D + lane * 2);
                        unsigned int x3 = *reinterpret_cast<const unsigned int*>(F + (size_t)q3 * D + lane * 2);
                        a[0] += (bflo(x0) + bflo(x1)) + (bflo(x2) + bflo(x3));
                        a[1] += (bfhi(x0) + bfhi(x1)) + (bfhi(x2) + bfhi(x3));
                    } else {
                        uint2 x0 = *reinterpret_cast<const uint2*>(F + (size_t)q0 * D + lane * 4);
                        uint2 x1 = *reinterpret_cast<const uint2*>(F + (size_t)q1 * D + lane * 4);
                        uint2 x2 = *reinterpret_cast<const uint2*>(F + (size_t)q2 * D + lane * 4);
                        uint2 x3 = *reinterpret_cast<const uint2*>(F + (size_t)q3 * D + lane * 4);
                        a[0] += (bflo(x0.x) + bflo(x1.x)) + (bflo(x2.x) + bflo(x3.x));
                        a[1] += (bfhi(x0.x) + bfhi(x1.x)) + (bfhi(x2.x) + bfhi(x3.x));
                        a[2] += (bflo(x0.y) + bflo(x1.y)) + (bflo(x2.y) + bflo(x3.y));
                        a[3] += (bfhi(x0.y) + bfhi(x1.y)) + (bfhi(x2.y) + bfhi(x3.y));
                    }
                }
                for (; i < m; i++) {
                    int q0 = __shfl(pw, i);
                    if (V == 2) {
                        unsigned int x0 = *reinterpret_cast<const unsigned int*>(F + (size_t)q0 * D + lane * 2);
                        a[0] += bflo(x0);
                        a[1] += bfhi(x0);
                    } else {
                        uint2 x0 = *reinterpret_cast<const uint2*>(F + (size_t)q0 * D + lane * 4);
                        a[0] += bflo(x0.x);
                        a[1] += bfhi(x0.x);
                        a[2] += bflo(x0.y);
                        a[3] += bfhi(x0.y);
                    }
                }
                j += m;
            }
            unsigned short* dst = AG + (size_t)n * (4 * D) + t * D + lane * V;
            if (V == 2) {
                unsigned int r = (unsigned int)f2bf(a[0] * inv) | ((unsigned int)f2bf(a[1] * inv) << 16);
                *reinterpret_cast<unsigned int*>(dst) = r;
            } else {
                uint2 r;
                r.x = (unsigned int)f2bf(a[0] * inv) | ((unsigned int)f2bf(a[1] * inv) << 16);
                r.y = (unsigned int)f2bf(a[2] * inv) | ((unsigned int)f2bf(a[3] * inv) << 16);
                *reinterpret_cast<uint2*>(dst) = r;
            }
            s0 = s1;
        }
    }
}

// ---------- MFMA GEMM: C[M,256] = [X | AG] @ WT^T + bias -------------------
// 64x64 tile, K-step 64, 4 waves in 2x2 (32x32 each). Grid: (N/64=4, M/64)
template <int D>
__global__ __launch_bounds__(256, 6) void gemm_kernel(
        const unsigned short* __restrict__ X,    // [M, D] bf16 (self features)
        const unsigned short* __restrict__ AG,   // [M, 4*D] bf16
        const unsigned short* __restrict__ BT,   // [256, 5*D] bf16
        const void* __restrict__ bias,           // [256] bf16 or f32 (flag)
        const int* __restrict__ flagp,
        unsigned short* __restrict__ C,          // [M, 256] bf16
        int M, int relu) {
    constexpr int K = 5 * D;
    constexpr int LDW = 72;                      // 64 + 8 pad, rows 16B-aligned
    __shared__ __align__(16) unsigned short As[64 * LDW];
    __shared__ __align__(16) unsigned short Bs[64 * LDW];
    int tid  = threadIdx.x;
    int n0   = blockIdx.x * 64;
    int m0   = blockIdx.y * 64;
    int wave = tid >> 6, lane = tid & 63;
    int wm = wave >> 1, wn = wave & 1;
    int quad = lane >> 4, l16 = lane & 15;

    f32x4 acc[2][2];
#pragma unroll
    for (int i = 0; i < 2; i++)
#pragma unroll
        for (int j = 0; j < 2; j++) acc[i][j] = (f32x4){0.f, 0.f, 0.f, 0.f};

    for (int k0 = 0; k0 < K; k0 += 64) {
        const unsigned short* base = (k0 < D) ? X : AG;
        int rs  = (k0 < D) ? D : 4 * D;
        int col = (k0 < D) ? k0 : (k0 - D);
#pragma unroll
        for (int cc = 0; cc < 2; cc++) {
            int c   = tid + cc * 256;      // 0..511
            int row = c >> 3;              // 8 uint4-chunks per 64-wide row
            int c8  = c & 7;
            uint4 va = make_uint4(0u, 0u, 0u, 0u);
            int gr = m0 + row;
            if (gr < M)
                va = *reinterpret_cast<const uint4*>(base + (size_t)gr * rs + col + c8 * 8);
            *reinterpret_cast<uint4*>(&As[row * LDW + c8 * 8]) = va;
            uint4 vb = *reinterpret_cast<const uint4*>(BT + (size_t)(n0 + row) * K + k0 + c8 * 8);
            *reinterpret_cast<uint4*>(&Bs[row * LDW + c8 * 8]) = vb;
        }
        __syncthreads();
#pragma unroll
        for (int ks = 0; ks < 2; ks++) {
            v8bf af[2], bfr[2];
#pragma unroll
            for (int i = 0; i < 2; i++)
                af[i] = *reinterpret_cast<const v8bf*>(
                    &As[(wm * 32 + i * 16 + l16) * LDW + ks * 32 + quad * 8]);
#pragma unroll
            for (int j = 0; j < 2; j++)
                bfr[j] = *reinterpret_cast<const v8bf*>(
                    &Bs[(wn * 32 + j * 16 + l16) * LDW + ks * 32 + quad * 8]);
#pragma unroll
            for (int i = 0; i < 2; i++)
#pragma unroll
                for (int j = 0; j < 2; j++)
                    acc[i][j] = __builtin_amdgcn_mfma_f32_16x16x32_bf16(af[i], bfr[j], acc[i][j], 0, 0, 0);
        }
        __syncthreads();
    }
    int bf = *flagp;
#pragma unroll
    for (int i = 0; i < 2; i++) {
#pragma unroll
        for (int j = 0; j < 2; j++) {
            int col = n0 + wn * 32 + j * 16 + l16;
            float bv = bf ? bf2f(((const unsigned short*)bias)[col])
                          : ((const float*)bias)[col];
#pragma unroll
            for (int r = 0; r < 4; r++) {
                int row = m0 + wm * 32 + i * 16 + quad * 4 + r;
                if (row < M) {
                    float v = acc[i][j][r] + bv;
                    if (relu) v = fmaxf(v, 0.0f);
                    C[(size_t)row * 256 + col] = f2bf(v);
                }
            }
        }
    }
}

// ---------- classifier head ------------------------------------------------
__global__ void cls_kernel(const unsigned short* __restrict__ h2,  // [N,256] bf16
                           const int* __restrict__ aidx,
                           const void* __restrict__ Wc,            // [256,3]
                           const void* __restrict__ bc,            // [3]
                           const int* __restrict__ flagp,
                           void* __restrict__ out) {               // [A,3]
    int lin = blockIdx.x * blockDim.x + threadIdx.x;
    int a = lin >> 6, lane = lin & 63;
    if (a >= N_ASPECTS) return;
    int bf = *flagp;
    int node = aidx[a];
    uint2 v = *reinterpret_cast<const uint2*>(h2 + (size_t)node * 256 + lane * 4);
    float hv[4] = {bflo(v.x), bfhi(v.x), bflo(v.y), bfhi(v.y)};
    float a0 = 0.f, a1 = 0.f, a2 = 0.f;
#pragma unroll
    for (int r = 0; r < 4; r++) {
        int k = lane * 4 + r;
        float w0 = bf ? bf2f(((const unsigned short*)Wc)[k * 3 + 0]) : ((const float*)Wc)[k * 3 + 0];
        float w1 = bf ? bf2f(((const unsigned short*)Wc)[k * 3 + 1]) : ((const float*)Wc)[k * 3 + 1];
        float w2 = bf ? bf2f(((const unsigned short*)Wc)[k * 3 + 2]) : ((const float*)Wc)[k * 3 + 2];
        a0 += hv[r] * w0;
        a1 += hv[r] * w1;
        a2 += hv[r] * w2;
    }
#pragma unroll
    for (int off = 32; off >= 1; off >>= 1) {
        a0 += __shfl_down(a0, off);
        a1 += __shfl_down(a1, off);
        a2 += __shfl_down(a2, off);
    }
    if (lane == 0) {
        float b0 = bf ? bf2f(((const unsigned short*)bc)[0]) : ((const float*)bc)[0];
        float b1 = bf ? bf2f(((const unsigned short*)bc)[1]) : ((const float*)bc)[1];
        float b2 = bf ? bf2f(((const unsigned short*)bc)[2]) : ((const float*)bc)[2];
        if (bf) {
            unsigned short* o = (unsigned short*)out;
            o[a * 3 + 0] = f2bf(a0 + b0);
            o[a * 3 + 1] = f2bf(a1 + b1);
            o[a * 3 + 2] = f2bf(a2 + b2);
        } else {
            float* o = (float*)out;
            o[a * 3 + 0] = a0 + b0;
            o[a * 3 + 1] = a1 + b1;
            o[a * 3 + 2] = a2 + b2;
        }
    }
}

extern "C" void kernel_launch(void* const* d_in, const int* in_sizes, int n_in,
                              void* d_out, int out_size, void* d_ws, size_t ws_size,
                              hipStream_t stream) {
    const void* x   = d_in[0];
    const void* Wt1 = d_in[1];
    const void* Ws1 = d_in[2];
    const void* b1  = d_in[3];
    const void* Wt2 = d_in[4];
    const void* Ws2 = d_in[5];
    const void* b2  = d_in[6];
    const void* Wc  = d_in[7];
    const void* bc  = d_in[8];
    const int* ei = (const int*)d_in[9];
    const int* et = (const int*)d_in[10];
    const int* ai = (const int*)d_in[11];

    char* ws = (char*)d_ws;
    size_t off = 0;
    auto alloc = [&](size_t bytes) {
        void* p = ws + off;
        off += (bytes + 255) & ~(size_t)255;
        return p;
    };
    int*            flag          = (int*)alloc(4);
    int*            bucket_cursor = (int*)alloc((size_t)NBUCK * 4);
    int*            out_base      = (int*)alloc((size_t)NBUCK * 4);
    int*            offsets4      = (int*)alloc((size_t)(NT4 + 1) * 4);
    unsigned int*   breg          = (unsigned int*)alloc((size_t)NBUCK * BCAP * 4); // 3.2 MB
    unsigned short* perm          = (unsigned short*)alloc((size_t)N_EDGES * 2);
    unsigned short* xc            = (unsigned short*)alloc((size_t)N_NODES * IN_DIM * 2);
    unsigned short* AG            = (unsigned short*)alloc((size_t)N_NODES * 4 * HID_DIM * 2);
    unsigned short* h             = (unsigned short*)alloc((size_t)N_NODES * HID_DIM * 2);
    unsigned short* h2            = (unsigned short*)alloc((size_t)N_NODES * HID_DIM * 2);
    unsigned short* WT1           = (unsigned short*)alloc((size_t)640 * 256 * 2);
    unsigned short* WT2           = (unsigned short*)alloc((size_t)1280 * 256 * 2);
    // total ~52 MB

    // fused preprocessing (detect/convx/packW1/packW2/cursor-zero): 3171 blocks
    pre_kernel<<<3171, 256, 0, stream>>>(x, Ws1, Wt1, Ws2, Wt2,
                                         xc, WT1, WT2, bucket_cursor, flag);

    // sort-based CSR build
    bucketA_kernel<<<N_EDGES / CHUNK, 256, 0, stream>>>(ei, et, bucket_cursor, breg);
    scan157_kernel<<<1, 256, 0, stream>>>(bucket_cursor, out_base, offsets4);
    bucketB_kernel<<<NBUCK, 256, 0, stream>>>(breg, bucket_cursor, out_base, perm, offsets4);

    // Layer 1
    agg_kernel<IN_DIM><<<2048, 256, 0, stream>>>(xc, offsets4, perm, AG);
    gemm_kernel<IN_DIM><<<dim3(4, 313), 256, 0, stream>>>(xc, AG, WT1, b1, flag, h, N_NODES, 1);
    // Layer 2
    agg_kernel<HID_DIM><<<2048, 256, 0, stream>>>(h, offsets4, perm, AG);
    gemm_kernel<HID_DIM><<<dim3(4, 313), 256, 0, stream>>>(h, AG, WT2, b2, flag, h2, N_NODES, 0);
    // Head
    cls_kernel<<<(N_ASPECTS * 64) / 256, 256, 0, stream>>>(h2, ai, Wc, bc, flag, d_out);
}